// Round 16
// baseline (512.343 us; speedup 1.0000x reference)
//
#include <hip/hip_runtime.h>
#include <hip/hip_bf16.h>
#include <stdint.h>

#define M_DIM 8192
#define K_DIM 512
#define N_DIM 32000

typedef short bf16x8 __attribute__((ext_vector_type(8)));
typedef float f32x4 __attribute__((ext_vector_type(4)));
typedef unsigned short u16;

__device__ __forceinline__ u16 f2bf(float f) {
  union { float f; uint32_t u; } v; v.f = f;
  uint32_t r = (v.u + 0x7fffu + ((v.u >> 16) & 1u)) >> 16;  // RNE
  return (u16)r;
}

// ---------------- Kernel 0: zero the column-sumsq accumulator ----------------
__global__ void k_zero(float* __restrict__ cn) {
  cn[blockIdx.x * 256 + threadIdx.x] = 0.f;
}

// ---------------- Kernel 1: row-l2norm of x -> bf16, one wave per row ----------------
__global__ void k_xnorm(const float* __restrict__ x, u16* __restrict__ xn) {
  int row = (blockIdx.x * blockDim.x + threadIdx.x) >> 6;
  int lane = threadIdx.x & 63;
  const float4* rp = (const float4*)(x + (size_t)row * K_DIM);
  float4 a = rp[lane];
  float4 b = rp[lane + 64];
  float s = a.x*a.x + a.y*a.y + a.z*a.z + a.w*a.w
          + b.x*b.x + b.y*b.y + b.z*b.z + b.w*b.w;
#pragma unroll
  for (int off = 32; off > 0; off >>= 1) s += __shfl_xor(s, off, 64);
  float r = rsqrtf(fmaxf(s, 1e-12f));
  ushort4 o0 = make_ushort4(f2bf(a.x*r), f2bf(a.y*r), f2bf(a.z*r), f2bf(a.w*r));
  ushort4 o1 = make_ushort4(f2bf(b.x*r), f2bf(b.y*r), f2bf(b.z*r), f2bf(b.w*r));
  ushort4* dst = (ushort4*)(xn + (size_t)row * K_DIM);
  dst[lane] = o0;
  dst[lane + 64] = o1;
}

// ---------------- Kernel 2: transpose + cast (UNNORMALIZED) + fused col-sumsq ----------------
__global__ void k_wtrans(const float* __restrict__ w, float* __restrict__ cn,
                         u16* __restrict__ wT) {
  __shared__ u16 tile[64][68];
  int c0 = blockIdx.x * 64;
  int r0 = blockIdx.y * 64;
  int tc = threadIdx.x & 63;
  int tw = threadIdx.x >> 6;  // 0..3
  float s = 0.f;
#pragma unroll
  for (int i = 0; i < 16; ++i) {
    int r = i * 4 + tw;
    float v = w[(size_t)(r0 + r) * N_DIM + c0 + tc];
    s = fmaf(v, v, s);
    tile[tc][r] = f2bf(v);
  }
  atomicAdd(&cn[c0 + tc], s);
  __syncthreads();
  int cc = threadIdx.x >> 4;        // 0..15
  int rr = (threadIdx.x & 15) * 4;  // 0..60
#pragma unroll
  for (int i = 0; i < 4; ++i) {
    int c = cc + i * 16;
    ushort4 v = *(const ushort4*)&tile[c][rr];
    *(ushort4*)(wT + (size_t)(c0 + c) * K_DIM + r0 + rr) = v;
  }
}

// ---------------- Kernel 3: PERSISTENT XCD-BANDED 128x128 GEMM, SINGLE-BUF, 4 blocks/CU ----------------
// m97-style 2-barrier kt: [frags+MFMA] -> sync -> [stage next] -> sync.
// 32 KB LDS + launch_bounds(256,4) -> 4 blocks/CU = 4 waves/SIMD: the exposed
// stage latency and per-tile NT-store drains are covered by 3 sibling blocks
// (TLP -- the only lever that has measured on this problem).
// XCD (b&7) owns bm band [xcd*8,xcd*8+8); worker blk=b>>3 (0..127):
// bm = xcd*8+(blk&7) FIXED, walks bn = (blk>>3) + 16*ti.
__global__ __launch_bounds__(256, 4) void k_gemm(const u16* __restrict__ A,
                                                 const u16* __restrict__ Bt,
                                                 const float* __restrict__ cn,
                                                 float* __restrict__ C) {
  __shared__ u16 sm[16384];  // single buffer: A [128][64] @0, B [128][64] @8192
  constexpr int BOFF = 8192;

  const int b = blockIdx.x;
  const int xcd = b & 7;
  const int blk = b >> 3;               // 0..127 worker within XCD
  const int bm = xcd * 8 + (blk & 7);   // FIXED per worker
  const int bn0 = blk >> 3;             // 0..15
  const int cnt = (bn0 < 10) ? 16 : 15; // bn = bn0 + 16*ti < 250

  const int tid = threadIdx.x;
  const int lane = tid & 63;
  const int w = tid >> 6;   // 0..3
  const int wr = w >> 1;    // 0..1 (64-row half)
  const int wc = w & 1;     // 0..1 (64-col half)
  const int la = lane & 15;
  const int lk = lane >> 4;
  const int rx = la & 7;
  const int s0 = ((0 + lk) ^ rx) * 8;  // swizzled elem-col, kk=0
  const int s1 = ((4 + lk) ^ rx) * 8;  // swizzled elem-col, kk=32

  // staging (rule #21: linear LDS dest + inverse-swizzled global src)
  const int srow = tid >> 3;                    // 0..31 (+ i*32)
  const int sgl = ((tid & 7) ^ (srow & 7)) * 8; // pre-swizzled global elem col
  const int ldst = srow * 64 + (tid & 7) * 8;   // linear LDS elem offset
  const int arow0 = (wr * 64 + la) * 64;        // + m*1024
  const int brow0 = (wc * 64 + la) * 64;        // + n*1024

  const u16* ag = A + (size_t)(bm * 128 + srow) * K_DIM + sgl;  // fixed all run
  int bn = bn0;
  const u16* bg = Bt + (size_t)(bn * 128 + srow) * K_DIM + sgl;
  constexpr size_t BSTEP = (size_t)16 * 128 * K_DIM;  // bn += 16

  f32x4 acc[4][4] = {};

#define GLL(p, eoff)                                                              \
  __builtin_amdgcn_global_load_lds(                                              \
      (const __attribute__((address_space(1))) void*)(p),                        \
      (__attribute__((address_space(3))) void*)&sm[(eoff)], 16, 0, 0)
#define STAGE(pa, pb)                                                             \
  { _Pragma("unroll")                                                             \
    for (int i = 0; i < 4; ++i) GLL((pa) + (size_t)i * 32 * K_DIM, i * 2048 + ldst); \
    _Pragma("unroll")                                                             \
    for (int i = 0; i < 4; ++i) GLL((pb) + (size_t)i * 32 * K_DIM, BOFF + i * 2048 + ldst); }

  // prologue: stage (tile0, kt=0)
  STAGE(ag, bg);
  __syncthreads();  // vmcnt(0): buffer confirmed

  for (int ti = 0; ti < cnt; ++ti) {
    for (int kt = 0; kt < 8; ++kt) {
      // compute on the staged buffer: kk-half inner to keep VGPR low
#pragma unroll
      for (int h = 0; h < 2; ++h) {
        const int sh = h ? s1 : s0;
        bf16x8 bfr[4];
#pragma unroll
        for (int n = 0; n < 4; ++n)
          bfr[n] = *(const bf16x8*)&sm[BOFF + brow0 + n * 1024 + sh];
#pragma unroll
        for (int m = 0; m < 4; ++m) {
          bf16x8 af = *(const bf16x8*)&sm[arow0 + m * 1024 + sh];
#pragma unroll
          for (int n = 0; n < 4; ++n)
            acc[m][n] = __builtin_amdgcn_mfma_f32_16x16x32_bf16(af, bfr[n], acc[m][n], 0, 0, 0);
        }
      }
      __syncthreads();  // all reads of the buffer done

      if (kt < 7) {
        STAGE(ag + (kt + 1) * 64, bg + (kt + 1) * 64);
        __syncthreads();  // vmcnt(0): next kt confirmed
      }
    }

    // ---- tile epilogue: scale by rsqrt(col sumsq), fire-and-forget NT stores ----
    {
      const size_t crow0 = (size_t)bm * 128 + wr * 64 + lk * 4;
      const int ccol0 = bn * 128 + wc * 64 + la;
      float rs[4];
#pragma unroll
      for (int n = 0; n < 4; ++n)
        rs[n] = rsqrtf(fmaxf(cn[ccol0 + n * 16], 1e-12f));
#pragma unroll
      for (int m = 0; m < 4; ++m)
#pragma unroll
        for (int j = 0; j < 4; ++j) {
          float* cp = C + (crow0 + m * 16 + j) * N_DIM + ccol0;
#pragma unroll
          for (int n = 0; n < 4; ++n)
            __builtin_nontemporal_store(acc[m][n][j] * rs[n], cp + n * 16);
        }
#pragma unroll
      for (int m = 0; m < 4; ++m)
#pragma unroll
        for (int n = 0; n < 4; ++n)
          acc[m][n] = (f32x4){0.f, 0.f, 0.f, 0.f};
    }

    bn += 16;
    bg += BSTEP;

    if (ti + 1 < cnt) {
      STAGE(ag, bg);     // next tile, kt=0 (A panel re-stage hits L2)
      __syncthreads();   // drains epilogue stores + confirms stage; siblings cover
    }
  }
#undef GLL
#undef STAGE
}

// ---------------- launch ----------------
extern "C" void kernel_launch(void* const* d_in, const int* in_sizes, int n_in,
                              void* d_out, int out_size, void* d_ws, size_t ws_size,
                              hipStream_t stream) {
  const float* x = (const float*)d_in[0];   // [8192, 512]
  const float* w = (const float*)d_in[1];   // [512, 32000]
  float* out = (float*)d_out;               // [8192, 32000]

  char* ws = (char*)d_ws;
  float* cn = (float*)ws;                                    // 32000 f32 (sumsq)
  u16* xn = (u16*)(ws + 131072);                             // 8192*512 bf16
  u16* wT = (u16*)(ws + 131072 + (size_t)M_DIM * K_DIM * 2); // 32000*512 bf16

  k_zero<<<N_DIM / 256, 256, 0, stream>>>(cn);
  k_xnorm<<<M_DIM / 4, 256, 0, stream>>>(x, xn);
  k_wtrans<<<dim3(N_DIM / 64, K_DIM / 64), 256, 0, stream>>>(w, cn, wT);
  k_gemm<<<1024, 256, 0, stream>>>(xn, wT, cn, out);
}

// Round 17
// 390.863 us; speedup vs baseline: 1.3108x; 1.3108x over previous
//
#include <hip/hip_runtime.h>
#include <hip/hip_bf16.h>
#include <stdint.h>

#define M_DIM 8192
#define K_DIM 512
#define N_DIM 32000

typedef short bf16x8 __attribute__((ext_vector_type(8)));
typedef float f32x16 __attribute__((ext_vector_type(16)));
typedef unsigned short u16;

__device__ __forceinline__ u16 f2bf(float f) {
  union { float f; uint32_t u; } v; v.f = f;
  uint32_t r = (v.u + 0x7fffu + ((v.u >> 16) & 1u)) >> 16;  // RNE
  return (u16)r;
}

// ---------------- Kernel 0: zero the column-sumsq accumulator ----------------
__global__ void k_zero(float* __restrict__ cn) {
  cn[blockIdx.x * 256 + threadIdx.x] = 0.f;
}

// ---------------- Kernel 1: row-l2norm of x -> bf16, one wave per row ----------------
__global__ void k_xnorm(const float* __restrict__ x, u16* __restrict__ xn) {
  int row = (blockIdx.x * blockDim.x + threadIdx.x) >> 6;
  int lane = threadIdx.x & 63;
  const float4* rp = (const float4*)(x + (size_t)row * K_DIM);
  float4 a = rp[lane];
  float4 b = rp[lane + 64];
  float s = a.x*a.x + a.y*a.y + a.z*a.z + a.w*a.w
          + b.x*b.x + b.y*b.y + b.z*b.z + b.w*b.w;
#pragma unroll
  for (int off = 32; off > 0; off >>= 1) s += __shfl_xor(s, off, 64);
  float r = rsqrtf(fmaxf(s, 1e-12f));
  ushort4 o0 = make_ushort4(f2bf(a.x*r), f2bf(a.y*r), f2bf(a.z*r), f2bf(a.w*r));
  ushort4 o1 = make_ushort4(f2bf(b.x*r), f2bf(b.y*r), f2bf(b.z*r), f2bf(b.w*r));
  ushort4* dst = (ushort4*)(xn + (size_t)row * K_DIM);
  dst[lane] = o0;
  dst[lane + 64] = o1;
}

// ---------------- Kernel 2: transpose + cast (UNNORMALIZED) + fused col-sumsq ----------------
__global__ void k_wtrans(const float* __restrict__ w, float* __restrict__ cn,
                         u16* __restrict__ wT) {
  __shared__ u16 tile[64][68];
  int c0 = blockIdx.x * 64;
  int r0 = blockIdx.y * 64;
  int tc = threadIdx.x & 63;
  int tw = threadIdx.x >> 6;  // 0..3
  float s = 0.f;
#pragma unroll
  for (int i = 0; i < 16; ++i) {
    int r = i * 4 + tw;
    float v = w[(size_t)(r0 + r) * N_DIM + c0 + tc];
    s = fmaf(v, v, s);
    tile[tc][r] = f2bf(v);
  }
  atomicAdd(&cn[c0 + tc], s);
  __syncthreads();
  int cc = threadIdx.x >> 4;        // 0..15
  int rr = (threadIdx.x & 15) * 4;  // 0..60
#pragma unroll
  for (int i = 0; i < 4; ++i) {
    int c = cc + i * 16;
    ushort4 v = *(const ushort4*)&tile[c][rr];
    *(ushort4*)(wT + (size_t)(c0 + c) * K_DIM + r0 + rr) = v;
  }
}

// ---------------- Kernel 3: PERSISTENT XCD-BANDED 128x128 GEMM, 32x32x16 MFMA ----------------
// R9 structure verbatim (banding, 2 blocks/CU, dbuf, NT stores, one sync/kt);
// ONLY change: v_mfma_f32_32x32x16_bf16 (16 instrs/wave/kt instead of 32 of
// 16x16x32; same fragment bytes, ~15% faster matrix pipe per m119, half the
// MFMA issue slots). Wave = 2x2 tiles of 32x32; acc = 4 x f32x16 (64 VGPR).
__global__ __launch_bounds__(256, 2) void k_gemm(const u16* __restrict__ A,
                                                 const u16* __restrict__ Bt,
                                                 const float* __restrict__ cn,
                                                 float* __restrict__ C) {
  __shared__ u16 sm[2][16384];  // per buf: A [128][64] @0, B [128][64] @8192
  constexpr int BOFF = 8192;

  const int b = blockIdx.x;
  const int xcd = b & 7;
  const int blk = b >> 3;              // 0..63 worker within XCD
  const int bm = xcd * 8 + (blk & 7);  // FIXED per worker
  const int bn0 = blk >> 3;            // 0..7
  const int cnt = (bn0 < 2) ? 32 : 31; // bn = bn0 + 8*ti < 250

  const int tid = threadIdx.x;
  const int lane = tid & 63;
  const int w = tid >> 6;    // 0..3
  const int wr = w >> 1;     // 0..1 (64-row half)
  const int wc = w & 1;      // 0..1 (64-col half)
  const int la5 = lane & 31; // row within 32x32 tile
  const int ks5 = lane >> 5; // k-half slot (0/1)
  const int rx = la5 & 7;

  // read-side swizzled slots: logical slot (2*ks + ks5) at physical ^ (row&7)
  int sr[4];
#pragma unroll
  for (int ks = 0; ks < 4; ++ks) sr[ks] = ((2 * ks + ks5) ^ rx) * 8;

  // staging (rule #21: linear LDS dest + inverse-swizzled global src) -- R9 verbatim
  const int srow = tid >> 3;                    // 0..31 (+ i*32)
  const int sgl = ((tid & 7) ^ (srow & 7)) * 8; // pre-swizzled global elem col
  const int ldst = srow * 64 + (tid & 7) * 8;   // linear LDS elem offset

  const u16* ag = A + (size_t)(bm * 128 + srow) * K_DIM + sgl;  // fixed all run
  int bn = bn0;
  const u16* bg = Bt + (size_t)(bn * 128 + srow) * K_DIM + sgl;
  constexpr size_t BSTEP = (size_t)8 * 128 * K_DIM;  // bn += 8

  // fragment row bases (elems): A rows wr*64 + mi*32 + la5; B rows wc*64 + ni*32 + la5
  const int arow0 = (wr * 64 + la5) * 64;  // + mi*32*64
  const int brow0 = (wc * 64 + la5) * 64;  // + ni*32*64

  f32x16 acc[2][2] = {};

#define GLL(p, eoff)                                                              \
  __builtin_amdgcn_global_load_lds(                                              \
      (const __attribute__((address_space(1))) void*)(p),                        \
      (__attribute__((address_space(3))) void*)&sm[0][(eoff)], 16, 0, 0)

  // prologue: stage (tile0, kt=0) into buf 0
#pragma unroll
  for (int i = 0; i < 4; ++i) GLL(ag + (size_t)i * 32 * K_DIM, i * 2048 + ldst);
#pragma unroll
  for (int i = 0; i < 4; ++i) GLL(bg + (size_t)i * 32 * K_DIM, BOFF + i * 2048 + ldst);
  __syncthreads();

  for (int ti = 0; ti < cnt; ++ti) {
    const bool last_tile = (ti + 1 == cnt);

    for (int kt = 0; kt < 8; ++kt) {
      const int cur = kt & 1;
      const int nxt = cur ^ 1;
      const bool pf = (kt < 7) || !last_tile;
      const u16* agk = (kt < 7) ? (ag + (kt + 1) * 64) : ag;           // next tile: same A panel
      const u16* bgk = (kt < 7) ? (bg + (kt + 1) * 64) : (bg + BSTEP); // next tile: bn+8

      // stage next K-step (issue early; drained by the kt-end __syncthreads)
      if (pf) {
        const int nb = nxt * 16384;
#pragma unroll
        for (int i = 0; i < 4; ++i) GLL(agk + (size_t)i * 32 * K_DIM, nb + i * 2048 + ldst);
#pragma unroll
        for (int i = 0; i < 4; ++i) GLL(bgk + (size_t)i * 32 * K_DIM, nb + BOFF + i * 2048 + ldst);
      }

      // fragments: 8 B + 8 A ds_read_b128 for 16 MFMA(32x32x16)
      bf16x8 bfr[2][4];
#pragma unroll
      for (int ni = 0; ni < 2; ++ni)
#pragma unroll
        for (int ks = 0; ks < 4; ++ks)
          bfr[ni][ks] = *(const bf16x8*)&sm[cur][BOFF + brow0 + ni * 2048 + sr[ks]];
#pragma unroll
      for (int mi = 0; mi < 2; ++mi)
#pragma unroll
        for (int ks = 0; ks < 4; ++ks) {
          bf16x8 af = *(const bf16x8*)&sm[cur][arow0 + mi * 2048 + sr[ks]];
#pragma unroll
          for (int ni = 0; ni < 2; ++ni)
            acc[mi][ni] = __builtin_amdgcn_mfma_f32_32x32x16_bf16(af, bfr[ni][ks], acc[mi][ni], 0, 0, 0);
        }

      __syncthreads();  // buf[nxt] staged + all reads of buf[cur] done
    }

    // ---- tile epilogue: scale by rsqrt(col sumsq), NT stores ----
    // C/D 32x32 layout [m74/m101]: col = lane&31, row = (reg&3) + 8*(reg>>2) + 4*(lane>>5)
    {
      const size_t crow_b = (size_t)bm * 128 + wr * 64 + 4 * ks5;
      const int ccol0 = bn * 128 + wc * 64 + la5;
      float rs[2];
#pragma unroll
      for (int ni = 0; ni < 2; ++ni)
        rs[ni] = rsqrtf(fmaxf(cn[ccol0 + ni * 32], 1e-12f));
#pragma unroll
      for (int mi = 0; mi < 2; ++mi)
#pragma unroll
        for (int reg = 0; reg < 16; ++reg) {
          const size_t row = crow_b + mi * 32 + (reg & 3) + 8 * (reg >> 2);
          float* cp = C + row * N_DIM + ccol0;
#pragma unroll
          for (int ni = 0; ni < 2; ++ni)
            __builtin_nontemporal_store(acc[mi][ni][reg] * rs[ni], cp + ni * 32);
        }
#pragma unroll
      for (int mi = 0; mi < 2; ++mi)
#pragma unroll
        for (int ni = 0; ni < 2; ++ni)
          acc[mi][ni] = (f32x16){0.f, 0.f, 0.f, 0.f, 0.f, 0.f, 0.f, 0.f,
                                 0.f, 0.f, 0.f, 0.f, 0.f, 0.f, 0.f, 0.f};
    }

    bn += 8;
    bg += BSTEP;
  }
#undef GLL
}

// ---------------- launch ----------------
extern "C" void kernel_launch(void* const* d_in, const int* in_sizes, int n_in,
                              void* d_out, int out_size, void* d_ws, size_t ws_size,
                              hipStream_t stream) {
  const float* x = (const float*)d_in[0];   // [8192, 512]
  const float* w = (const float*)d_in[1];   // [512, 32000]
  float* out = (float*)d_out;               // [8192, 32000]

  char* ws = (char*)d_ws;
  float* cn = (float*)ws;                                    // 32000 f32 (sumsq)
  u16* xn = (u16*)(ws + 131072);                             // 8192*512 bf16
  u16* wT = (u16*)(ws + 131072 + (size_t)M_DIM * K_DIM * 2); // 32000*512 bf16

  k_zero<<<N_DIM / 256, 256, 0, stream>>>(cn);
  k_xnorm<<<M_DIM / 4, 256, 0, stream>>>(x, xn);
  k_wtrans<<<dim3(N_DIM / 64, K_DIM / 64), 256, 0, stream>>>(w, cn, wT);
  k_gemm<<<512, 256, 0, stream>>>(xn, wT, cn, out);
}